// Round 5
// baseline (5312.821 us; speedup 1.0000x reference)
//
#include <hip/hip_runtime.h>
#include <cstdint>
#include <cstddef>

#define S_LEN 2048
#define BATCH 2
#define HIDN  2048
#define NHEAD 16
#define DHEAD 128
#define NQKV  6144   // 3*NHEAD*DHEAD
#define MROWS 4096   // S_LEN*BATCH

typedef unsigned short u16;
typedef __attribute__((ext_vector_type(8))) __bf16 bf16x8;
typedef __attribute__((ext_vector_type(4))) float f32x4;

__device__ __forceinline__ float bf2f(u16 u) {
  union { uint32_t i; float f; } v; v.i = ((uint32_t)u) << 16; return v.f;
}
__device__ __forceinline__ u16 f2bf(float f) {
  union { float f; uint32_t i; } v; v.f = f;
  uint32_t r = v.i + 0x7fffu + ((v.i >> 16) & 1u);
  return (u16)(r >> 16);
}

__device__ __forceinline__ void async_cp16(const u16* g, u16* l) {
  __builtin_amdgcn_global_load_lds(
      (const __attribute__((address_space(1))) void*)g,
      (__attribute__((address_space(3))) void*)l, 16, 0, 0);
}

// ---------------- hidden canonicalize: fp32[N] -> bf16[N] --------------------
__global__ __launch_bounds__(256) void convert_hidden_kernel(
    const float* __restrict__ src, u16* __restrict__ out) {
  size_t c = (size_t)blockIdx.x * 256 + threadIdx.x;  // chunk of 8 elements
  const float4* in = (const float4*)(src + c * 8);
  float4 v0 = in[0], v1 = in[1];
  u16 t[8] = {f2bf(v0.x), f2bf(v0.y), f2bf(v0.z), f2bf(v0.w),
              f2bf(v1.x), f2bf(v1.y), f2bf(v1.z), f2bf(v1.w)};
  *(uint4*)&out[c * 8] = *(const uint4*)t;
}

// ---------------- transpose+cast: fp32 in[R][C] -> bf16 out[C][R] ------------
__global__ __launch_bounds__(256) void transpose_kernel(
    const float* __restrict__ in, u16* __restrict__ out, int R, int C) {
  __shared__ u16 tile[64][72];
  const int bx = blockIdx.x * 64;  // col base in `in`
  const int by = blockIdx.y * 64;  // row base in `in`
  const int lx = threadIdx.x & 15, ly = threadIdx.x >> 4;
#pragma unroll
  for (int i = 0; i < 4; i++) {
    int r = ly * 4 + i;
    float4 v = *(const float4*)&in[(size_t)(by + r) * C + bx + lx * 4];
    tile[r][lx * 4 + 0] = f2bf(v.x); tile[r][lx * 4 + 1] = f2bf(v.y);
    tile[r][lx * 4 + 2] = f2bf(v.z); tile[r][lx * 4 + 3] = f2bf(v.w);
  }
  __syncthreads();
#pragma unroll
  for (int i = 0; i < 4; i++) {
    int oc = ly * 4 + i;  // out row = bx + oc
    ushort4 o;
    o.x = tile[lx * 4 + 0][oc]; o.y = tile[lx * 4 + 1][oc];
    o.z = tile[lx * 4 + 2][oc]; o.w = tile[lx * 4 + 3][oc];
    *(ushort4*)&out[(size_t)(bx + oc) * R + by + lx * 4] = o;
  }
}

// ---------------- bf16 per-head transpose: Vt[bh][d][s] -> Vb[bh][s][d] ------
__global__ __launch_bounds__(256) void vtrans_kernel(
    const u16* __restrict__ Vt, u16* __restrict__ Vb) {
  __shared__ u16 tile[64][72];
  const int bh = blockIdx.z;
  const u16* in = Vt + (size_t)bh * DHEAD * S_LEN;   // [128 d][2048 s]
  u16* out = Vb + (size_t)bh * S_LEN * DHEAD;        // [2048 s][128 d]
  const int bx = blockIdx.x * 64;  // s base
  const int by = blockIdx.y * 64;  // d base
  const int lx = threadIdx.x & 15, ly = threadIdx.x >> 4;
#pragma unroll
  for (int i = 0; i < 4; i++) {
    int r = ly * 4 + i;  // d offset
    ushort4 v = *(const ushort4*)&in[(size_t)(by + r) * S_LEN + bx + lx * 4];
    tile[r][lx * 4 + 0] = v.x; tile[r][lx * 4 + 1] = v.y;
    tile[r][lx * 4 + 2] = v.z; tile[r][lx * 4 + 3] = v.w;
  }
  __syncthreads();
#pragma unroll
  for (int i = 0; i < 4; i++) {
    int oc = ly * 4 + i;  // s offset
    ushort4 o;
    o.x = tile[lx * 4 + 0][oc]; o.y = tile[lx * 4 + 1][oc];
    o.z = tile[lx * 4 + 2][oc]; o.w = tile[lx * 4 + 3][oc];
    *(ushort4*)&out[(size_t)(bx + oc) * DHEAD + by + lx * 4] = o;
  }
}

// ---------------- QKV GEMM: [4096,2048] x Wt[6144,2048] + bias ---------------
__global__ __launch_bounds__(256) void gemm_qkv_kernel(
    const u16* __restrict__ A, const u16* __restrict__ Bt,
    const float* __restrict__ bias,
    u16* __restrict__ Qb, u16* __restrict__ Kb, u16* __restrict__ Vt) {
  __shared__ __align__(16) u16 lds_a[128 * 32];
  __shared__ __align__(16) u16 lds_b[128 * 32];
  const int tid = threadIdx.x;
  const int wave = tid >> 6, lane = tid & 63;
  const int lhi = lane >> 4, llo = lane & 15;
  const int m0 = blockIdx.y * 128, n0 = blockIdx.x * 128;
  const int wm = (wave >> 1) * 64, wn = (wave & 1) * 64;
  const int K = HIDN;

  f32x4 acc[4][4] = {};

  const int srow = tid >> 2;
  const int skoff = (tid & 3) * 8;
  const u16* ap0 = A + (size_t)(m0 + srow) * K + skoff;
  const u16* ap1 = A + (size_t)(m0 + 64 + srow) * K + skoff;
  const u16* bp0 = Bt + (size_t)(n0 + srow) * K + skoff;
  const u16* bp1 = Bt + (size_t)(n0 + 64 + srow) * K + skoff;
  u16* la0 = lds_a + tid * 8;
  u16* la1 = lds_a + 2048 + tid * 8;
  u16* lb0 = lds_b + tid * 8;
  u16* lb1 = lds_b + 2048 + tid * 8;

  for (int k0 = 0; k0 < K; k0 += 32) {
    async_cp16(ap0 + k0, la0);
    async_cp16(ap1 + k0, la1);
    async_cp16(bp0 + k0, lb0);
    async_cp16(bp1 + k0, lb1);
    __syncthreads();
    bf16x8 af[4], bfr[4];
#pragma unroll
    for (int i = 0; i < 4; i++)
      af[i] = *(const bf16x8*)&lds_a[(wm + i * 16 + llo) * 32 + lhi * 8];
#pragma unroll
    for (int j = 0; j < 4; j++)
      bfr[j] = *(const bf16x8*)&lds_b[(wn + j * 16 + llo) * 32 + lhi * 8];
#pragma unroll
    for (int i = 0; i < 4; i++)
#pragma unroll
      for (int j = 0; j < 4; j++)
        acc[i][j] = __builtin_amdgcn_mfma_f32_16x16x32_bf16(af[i], bfr[j], acc[i][j], 0, 0, 0);
    __syncthreads();
  }

#pragma unroll
  for (int i = 0; i < 4; i++) {
#pragma unroll
    for (int j = 0; j < 4; j++) {
      int col = n0 + wn + j * 16 + llo;       // 0..6143
      int h = col / 384;
      int rr = col - h * 384;
      int part = rr >> 7;                     // 0=q 1=k 2=v
      int d = rr & 127;
      float bv = bias[col];
#pragma unroll
      for (int r = 0; r < 4; r++) {
        int row = m0 + wm + i * 16 + lhi * 4 + r;  // 0..4095
        int s = row >> 1, b = row & 1;
        int bh = b * NHEAD + h;
        u16 o = f2bf(acc[i][j][r] + bv);
        if (part == 0)      Qb[((size_t)bh * S_LEN + s) * DHEAD + d] = o;
        else if (part == 1) Kb[((size_t)bh * S_LEN + s) * DHEAD + d] = o;
        else                Vt[((size_t)bh * DHEAD + d) * S_LEN + s] = o;
      }
    }
  }
}

// ------------- dense GEMM: ctx[4096,2048] x Wt[2048,2048] -> fp32 out --------
__global__ __launch_bounds__(256) void gemm_dense_kernel(
    const u16* __restrict__ A, const u16* __restrict__ Bt,
    float* __restrict__ out) {
  __shared__ __align__(16) u16 lds_a[128 * 32];
  __shared__ __align__(16) u16 lds_b[128 * 32];
  const int tid = threadIdx.x;
  const int wave = tid >> 6, lane = tid & 63;
  const int lhi = lane >> 4, llo = lane & 15;
  const int m0 = blockIdx.y * 128, n0 = blockIdx.x * 128;
  const int wm = (wave >> 1) * 64, wn = (wave & 1) * 64;
  const int K = HIDN;

  f32x4 acc[4][4] = {};

  const int srow = tid >> 2;
  const int skoff = (tid & 3) * 8;
  const u16* ap0 = A + (size_t)(m0 + srow) * K + skoff;
  const u16* ap1 = A + (size_t)(m0 + 64 + srow) * K + skoff;
  const u16* bp0 = Bt + (size_t)(n0 + srow) * K + skoff;
  const u16* bp1 = Bt + (size_t)(n0 + 64 + srow) * K + skoff;
  u16* la0 = lds_a + tid * 8;
  u16* la1 = lds_a + 2048 + tid * 8;
  u16* lb0 = lds_b + tid * 8;
  u16* lb1 = lds_b + 2048 + tid * 8;

  for (int k0 = 0; k0 < K; k0 += 32) {
    async_cp16(ap0 + k0, la0);
    async_cp16(ap1 + k0, la1);
    async_cp16(bp0 + k0, lb0);
    async_cp16(bp1 + k0, lb1);
    __syncthreads();
    bf16x8 af[4], bfr[4];
#pragma unroll
    for (int i = 0; i < 4; i++)
      af[i] = *(const bf16x8*)&lds_a[(wm + i * 16 + llo) * 32 + lhi * 8];
#pragma unroll
    for (int j = 0; j < 4; j++)
      bfr[j] = *(const bf16x8*)&lds_b[(wn + j * 16 + llo) * 32 + lhi * 8];
#pragma unroll
    for (int i = 0; i < 4; i++)
#pragma unroll
      for (int j = 0; j < 4; j++)
        acc[i][j] = __builtin_amdgcn_mfma_f32_16x16x32_bf16(af[i], bfr[j], acc[i][j], 0, 0, 0);
    __syncthreads();
  }

  // fp32 epilogue: reference output dtype is float32
#pragma unroll
  for (int i = 0; i < 4; i++)
#pragma unroll
    for (int j = 0; j < 4; j++) {
      int col = n0 + wn + j * 16 + llo;
#pragma unroll
      for (int r = 0; r < 4; r++) {
        int row = m0 + wm + i * 16 + lhi * 4 + r;
        out[(size_t)row * HIDN + col] = acc[i][j][r];
      }
    }
}

// ------------- simple attention (validation): 1 wave per (bh,s) --------------
__global__ __launch_bounds__(256) void simple_attn_kernel(
    const u16* __restrict__ Qb, const u16* __restrict__ Kb,
    const u16* __restrict__ Vb, u16* __restrict__ ctx) {
  const int wave = threadIdx.x >> 6, lane = threadIdx.x & 63;
  const int s = blockIdx.x * 4 + wave;   // 0..2047
  const int bh = blockIdx.y;             // 0..31
  const int b = bh >> 4, h = bh & 15;

  const u16* qp = Qb + ((size_t)bh * S_LEN + s) * DHEAD;
  uint32_t qu = *(const uint32_t*)&qp[lane * 2];
  float q0 = bf2f((u16)(qu & 0xFFFF)), q1 = bf2f((u16)(qu >> 16));

  const u16* kp = Kb + (size_t)bh * S_LEN * DHEAD;
  const u16* vp = Vb + (size_t)bh * S_LEN * DHEAD;
  const float sc = 0.08838834764831845f;  // 1/sqrt(128)

  float m = -1e30f, l = 0.f, c0 = 0.f, c1 = 0.f;
  for (int t = 0; t <= s; t++) {
    uint32_t ku = *(const uint32_t*)&kp[(size_t)t * DHEAD + lane * 2];
    float d = q0 * bf2f((u16)(ku & 0xFFFF)) + q1 * bf2f((u16)(ku >> 16));
#pragma unroll
    for (int off = 1; off < 64; off <<= 1) d += __shfl_xor(d, off, 64);
    float scv = d * sc;
    float mn = fmaxf(m, scv);
    float f = __expf(m - mn);
    float p = __expf(scv - mn);
    uint32_t vu = *(const uint32_t*)&vp[(size_t)t * DHEAD + lane * 2];
    l = l * f + p;
    c0 = c0 * f + p * bf2f((u16)(vu & 0xFFFF));
    c1 = c1 * f + p * bf2f((u16)(vu >> 16));
    m = mn;
  }
  float inv = 1.f / l;
  u16 o0 = f2bf(c0 * inv), o1 = f2bf(c1 * inv);
  uint32_t ow = (uint32_t)o0 | ((uint32_t)o1 << 16);
  *(uint32_t*)&ctx[((size_t)(s * BATCH + b)) * HIDN + h * DHEAD + lane * 2] = ow;
}

// ---------------- bias tail: fp32 copy into output slot 1 --------------------
__global__ __launch_bounds__(256) void bias_copy_kernel(
    const float* __restrict__ bsrc, float* __restrict__ dst) {
  int i = blockIdx.x * 256 + threadIdx.x;
  if (i < HIDN) dst[i] = bsrc[i];
}

extern "C" void kernel_launch(void* const* d_in, const int* in_sizes, int n_in,
                              void* d_out, int out_size, void* d_ws, size_t ws_size,
                              hipStream_t stream) {
  // Input mapping by unique element counts (mask shares W_dense's 4194304
  // count but precedes it in dict order -> take LAST match for W_dense).
  int i_hid = 0, i_w1 = 2, i_b1 = 3, i_w2 = 4, i_b2 = 5;
  for (int i = 0; i < n_in; i++) {
    int s = in_sizes[i];
    if (s == MROWS * HIDN)      i_hid = i;
    else if (s == HIDN * NQKV)  i_w1 = i;
    else if (s == NQKV)         i_b1 = i;
    else if (s == HIDN)         i_b2 = i;
  }
  for (int i = n_in - 1; i >= 0; i--)
    if (in_sizes[i] == HIDN * HIDN) { i_w2 = i; break; }

  const float* hidden  = (const float*)d_in[i_hid];
  const float* W_qkv   = (const float*)d_in[i_w1];
  const float* b_qkv   = (const float*)d_in[i_b1];
  const float* W_dense = (const float*)d_in[i_w2];
  const float* b_dense = (const float*)d_in[i_b2];
  float* out = (float*)d_out;   // fp32: reference output dtype

  // Workspace (72 MB peak):
  //   [0, 24M)  : Wq_t   (transpose#1 .. gemm_qkv)
  //   [0, 16M)  : ctx    (attn .. gemm_dense)  -- overlays dead Wq_t
  //   [16M,24M) : Wd_t   (transpose#2 .. gemm_dense)
  //   [24M,40M) : Qb   [40M,56M): Kb   [56M,72M): Vt
  // d_out (33.5 MB fp32): bytes [0,16M) host hidden_c (bf16) then Vb (bf16),
  // both dead before gemm_dense writes the fp32 result over [0,33.5M).
  char* ws = (char*)d_ws;
  u16* Wq_t = (u16*)(ws);
  u16* ctx  = (u16*)(ws);
  u16* Wd_t = (u16*)(ws + 16777216);
  u16* Qb   = (u16*)(ws + 25165824);
  u16* Kb   = (u16*)(ws + 41943040);
  u16* Vt   = (u16*)(ws + 58720256);
  u16* hidden_c = (u16*)d_out;  // bytes [0,16M) of d_out
  u16* Vb       = (u16*)d_out;  // same region, after hidden_c is dead

  convert_hidden_kernel<<<dim3(MROWS * HIDN / 8 / 256), 256, 0, stream>>>(hidden, hidden_c);
  transpose_kernel<<<dim3(NQKV / 64, HIDN / 64), 256, 0, stream>>>(W_qkv, Wq_t, HIDN, NQKV);
  gemm_qkv_kernel<<<dim3(NQKV / 128, MROWS / 128), 256, 0, stream>>>(hidden_c, Wq_t, b_qkv, Qb, Kb, Vt);
  vtrans_kernel<<<dim3(S_LEN / 64, DHEAD / 64, BATCH * NHEAD), 256, 0, stream>>>(Vt, Vb);
  simple_attn_kernel<<<dim3(S_LEN / 4, BATCH * NHEAD), 256, 0, stream>>>(Qb, Kb, Vb, ctx);
  transpose_kernel<<<dim3(HIDN / 64, HIDN / 64), 256, 0, stream>>>(W_dense, Wd_t, HIDN, HIDN);
  gemm_dense_kernel<<<dim3(HIDN / 128, MROWS / 128), 256, 0, stream>>>(ctx, Wd_t, out);
  bias_copy_kernel<<<dim3(8), 256, 0, stream>>>(b_dense, out + (size_t)MROWS * HIDN);
}

// Round 6
// 678.364 us; speedup vs baseline: 7.8318x; 7.8318x over previous
//
#include <hip/hip_runtime.h>
#include <cstdint>
#include <cstddef>

#define S_LEN 2048
#define BATCH 2
#define HIDN  2048
#define NHEAD 16
#define DHEAD 128
#define NQKV  6144   // 3*NHEAD*DHEAD
#define MROWS 4096   // S_LEN*BATCH

typedef unsigned short u16;
typedef __attribute__((ext_vector_type(8))) __bf16 bf16x8;
typedef __attribute__((ext_vector_type(4))) float f32x4;

__device__ __forceinline__ float bf2f(u16 u) {
  union { uint32_t i; float f; } v; v.i = ((uint32_t)u) << 16; return v.f;
}
__device__ __forceinline__ u16 f2bf(float f) {
  union { float f; uint32_t i; } v; v.f = f;
  uint32_t r = v.i + 0x7fffu + ((v.i >> 16) & 1u);
  return (u16)(r >> 16);
}

__device__ __forceinline__ void async_cp16(const u16* g, u16* l) {
  __builtin_amdgcn_global_load_lds(
      (const __attribute__((address_space(1))) void*)g,
      (__attribute__((address_space(3))) void*)l, 16, 0, 0);
}

// ---------------- hidden canonicalize: fp32[N] -> bf16[N] --------------------
__global__ __launch_bounds__(256) void convert_hidden_kernel(
    const float* __restrict__ src, u16* __restrict__ out) {
  size_t c = (size_t)blockIdx.x * 256 + threadIdx.x;  // chunk of 8 elements
  const float4* in = (const float4*)(src + c * 8);
  float4 v0 = in[0], v1 = in[1];
  u16 t[8] = {f2bf(v0.x), f2bf(v0.y), f2bf(v0.z), f2bf(v0.w),
              f2bf(v1.x), f2bf(v1.y), f2bf(v1.z), f2bf(v1.w)};
  *(uint4*)&out[c * 8] = *(const uint4*)t;
}

// ---------------- transpose+cast: fp32 in[R][C] -> bf16 out[C][R] ------------
__global__ __launch_bounds__(256) void transpose_kernel(
    const float* __restrict__ in, u16* __restrict__ out, int R, int C) {
  __shared__ u16 tile[64][72];
  const int bx = blockIdx.x * 64;  // col base in `in`
  const int by = blockIdx.y * 64;  // row base in `in`
  const int lx = threadIdx.x & 15, ly = threadIdx.x >> 4;
#pragma unroll
  for (int i = 0; i < 4; i++) {
    int r = ly * 4 + i;
    float4 v = *(const float4*)&in[(size_t)(by + r) * C + bx + lx * 4];
    tile[r][lx * 4 + 0] = f2bf(v.x); tile[r][lx * 4 + 1] = f2bf(v.y);
    tile[r][lx * 4 + 2] = f2bf(v.z); tile[r][lx * 4 + 3] = f2bf(v.w);
  }
  __syncthreads();
#pragma unroll
  for (int i = 0; i < 4; i++) {
    int oc = ly * 4 + i;  // out row = bx + oc
    ushort4 o;
    o.x = tile[lx * 4 + 0][oc]; o.y = tile[lx * 4 + 1][oc];
    o.z = tile[lx * 4 + 2][oc]; o.w = tile[lx * 4 + 3][oc];
    *(ushort4*)&out[(size_t)(bx + oc) * R + by + lx * 4] = o;
  }
}

// ---------------- QKV GEMM: [4096,2048] x Wt[6144,2048] + bias ---------------
__global__ __launch_bounds__(256) void gemm_qkv_kernel(
    const u16* __restrict__ A, const u16* __restrict__ Bt,
    const float* __restrict__ bias,
    u16* __restrict__ Qb, u16* __restrict__ Kb, u16* __restrict__ Vt) {
  __shared__ __align__(16) u16 lds_a[128 * 32];
  __shared__ __align__(16) u16 lds_b[128 * 32];
  const int tid = threadIdx.x;
  const int wave = tid >> 6, lane = tid & 63;
  const int lhi = lane >> 4, llo = lane & 15;
  const int m0 = blockIdx.y * 128, n0 = blockIdx.x * 128;
  const int wm = (wave >> 1) * 64, wn = (wave & 1) * 64;
  const int K = HIDN;

  f32x4 acc[4][4] = {};

  const int srow = tid >> 2;
  const int skoff = (tid & 3) * 8;
  const u16* ap0 = A + (size_t)(m0 + srow) * K + skoff;
  const u16* ap1 = A + (size_t)(m0 + 64 + srow) * K + skoff;
  const u16* bp0 = Bt + (size_t)(n0 + srow) * K + skoff;
  const u16* bp1 = Bt + (size_t)(n0 + 64 + srow) * K + skoff;
  u16* la0 = lds_a + tid * 8;
  u16* la1 = lds_a + 2048 + tid * 8;
  u16* lb0 = lds_b + tid * 8;
  u16* lb1 = lds_b + 2048 + tid * 8;

  for (int k0 = 0; k0 < K; k0 += 32) {
    async_cp16(ap0 + k0, la0);
    async_cp16(ap1 + k0, la1);
    async_cp16(bp0 + k0, lb0);
    async_cp16(bp1 + k0, lb1);
    __syncthreads();
    bf16x8 af[4], bfr[4];
#pragma unroll
    for (int i = 0; i < 4; i++)
      af[i] = *(const bf16x8*)&lds_a[(wm + i * 16 + llo) * 32 + lhi * 8];
#pragma unroll
    for (int j = 0; j < 4; j++)
      bfr[j] = *(const bf16x8*)&lds_b[(wn + j * 16 + llo) * 32 + lhi * 8];
#pragma unroll
    for (int i = 0; i < 4; i++)
#pragma unroll
      for (int j = 0; j < 4; j++)
        acc[i][j] = __builtin_amdgcn_mfma_f32_16x16x32_bf16(af[i], bfr[j], acc[i][j], 0, 0, 0);
    __syncthreads();
  }

#pragma unroll
  for (int i = 0; i < 4; i++) {
#pragma unroll
    for (int j = 0; j < 4; j++) {
      int col = n0 + wn + j * 16 + llo;       // 0..6143
      int h = col / 384;
      int rr = col - h * 384;
      int part = rr >> 7;                     // 0=q 1=k 2=v
      int d = rr & 127;
      float bv = bias[col];
#pragma unroll
      for (int r = 0; r < 4; r++) {
        int row = m0 + wm + i * 16 + lhi * 4 + r;  // 0..4095
        int s = row >> 1, b = row & 1;
        int bh = b * NHEAD + h;
        u16 o = f2bf(acc[i][j][r] + bv);
        if (part == 0)      Qb[((size_t)bh * S_LEN + s) * DHEAD + d] = o;
        else if (part == 1) Kb[((size_t)bh * S_LEN + s) * DHEAD + d] = o;
        else                Vt[((size_t)bh * DHEAD + d) * S_LEN + s] = o;
      }
    }
  }
}

// ------------- dense GEMM: ctx[4096,2048] x Wt[2048,2048] -> fp32 out --------
__global__ __launch_bounds__(256) void gemm_dense_kernel(
    const u16* __restrict__ A, const u16* __restrict__ Bt,
    float* __restrict__ out) {
  __shared__ __align__(16) u16 lds_a[128 * 32];
  __shared__ __align__(16) u16 lds_b[128 * 32];
  const int tid = threadIdx.x;
  const int wave = tid >> 6, lane = tid & 63;
  const int lhi = lane >> 4, llo = lane & 15;
  const int m0 = blockIdx.y * 128, n0 = blockIdx.x * 128;
  const int wm = (wave >> 1) * 64, wn = (wave & 1) * 64;
  const int K = HIDN;

  f32x4 acc[4][4] = {};

  const int srow = tid >> 2;
  const int skoff = (tid & 3) * 8;
  const u16* ap0 = A + (size_t)(m0 + srow) * K + skoff;
  const u16* ap1 = A + (size_t)(m0 + 64 + srow) * K + skoff;
  const u16* bp0 = Bt + (size_t)(n0 + srow) * K + skoff;
  const u16* bp1 = Bt + (size_t)(n0 + 64 + srow) * K + skoff;
  u16* la0 = lds_a + tid * 8;
  u16* la1 = lds_a + 2048 + tid * 8;
  u16* lb0 = lds_b + tid * 8;
  u16* lb1 = lds_b + 2048 + tid * 8;

  for (int k0 = 0; k0 < K; k0 += 32) {
    async_cp16(ap0 + k0, la0);
    async_cp16(ap1 + k0, la1);
    async_cp16(bp0 + k0, lb0);
    async_cp16(bp1 + k0, lb1);
    __syncthreads();
    bf16x8 af[4], bfr[4];
#pragma unroll
    for (int i = 0; i < 4; i++)
      af[i] = *(const bf16x8*)&lds_a[(wm + i * 16 + llo) * 32 + lhi * 8];
#pragma unroll
    for (int j = 0; j < 4; j++)
      bfr[j] = *(const bf16x8*)&lds_b[(wn + j * 16 + llo) * 32 + lhi * 8];
#pragma unroll
    for (int i = 0; i < 4; i++)
#pragma unroll
      for (int j = 0; j < 4; j++)
        acc[i][j] = __builtin_amdgcn_mfma_f32_16x16x32_bf16(af[i], bfr[j], acc[i][j], 0, 0, 0);
    __syncthreads();
  }

  // fp32 epilogue: reference output dtype is float32
#pragma unroll
  for (int i = 0; i < 4; i++)
#pragma unroll
    for (int j = 0; j < 4; j++) {
      int col = n0 + wn + j * 16 + llo;
#pragma unroll
      for (int r = 0; r < 4; r++) {
        int row = m0 + wm + i * 16 + lhi * 4 + r;
        out[(size_t)row * HIDN + col] = acc[i][j][r];
      }
    }
}

// ---------------- flash attention (causal), one block per (q-tile, bh) -------
__global__ __launch_bounds__(256, 1) void attn_kernel(
    const u16* __restrict__ Qb, const u16* __restrict__ Kb,
    const u16* __restrict__ Vt, u16* __restrict__ ctx) {
  const int qi = blockIdx.x;   // 0..15
  const int bh = blockIdx.y;   // 0..31
  const int b = bh >> 4, h = bh & 15;
  const int tid = threadIdx.x;
  const int wave = tid >> 6, lane = tid & 63;
  const int lhi = lane >> 4, llo = lane & 15;
  const int LP = 136;          // padded row stride (breaks 256B bank aliasing)
  __shared__ __align__(16) u16 lds_q[128 * 136];
  __shared__ __align__(16) u16 lds_k[128 * 136];
  __shared__ __align__(16) u16 lds_v[128 * 136];
  __shared__ __align__(16) u16 lds_p[128 * 136];

  {  // stage Q tile once (first in-loop barrier orders it before reads)
    const u16* src = Qb + ((size_t)bh * S_LEN + qi * 128) * DHEAD;
#pragma unroll
    for (int p = 0; p < 8; p++) {
      int idx = p * 256 + tid;
      int r = idx >> 4, sg = (idx & 15) * 8;
      *(uint4*)&lds_q[r * LP + sg] = *(const uint4*)&src[r * DHEAD + sg];
    }
  }

  f32x4 oacc[2][8] = {};
  float mrow[2][4], lrow[2][4];
#pragma unroll
  for (int i = 0; i < 2; i++)
#pragma unroll
    for (int r = 0; r < 4; r++) { mrow[i][r] = -1e30f; lrow[i][r] = 0.f; }

  const float sc = 0.08838834764831845f;  // 1/sqrt(128)

  for (int kt = 0; kt <= qi; kt++) {
    const u16* ksrc = Kb + ((size_t)bh * S_LEN + kt * 128) * DHEAD;
    const u16* vsrc = Vt + (size_t)bh * DHEAD * S_LEN + kt * 128;
#pragma unroll
    for (int p = 0; p < 8; p++) {
      int idx = p * 256 + tid;
      int r = idx >> 4, sg = (idx & 15) * 8;
      *(uint4*)&lds_k[r * LP + sg] = *(const uint4*)&ksrc[r * DHEAD + sg];
      *(uint4*)&lds_v[r * LP + sg] = *(const uint4*)&vsrc[(size_t)r * S_LEN + sg];
    }
    __syncthreads();

    // S = Q K^T  (wave owns 32 q-rows x 128 t-cols)
    f32x4 sacc[2][8] = {};
#pragma unroll
    for (int kk = 0; kk < 4; kk++) {
      bf16x8 aq[2];
#pragma unroll
      for (int i = 0; i < 2; i++)
        aq[i] = *(const bf16x8*)&lds_q[(wave * 32 + i * 16 + llo) * LP + kk * 32 + lhi * 8];
#pragma unroll
      for (int j = 0; j < 8; j++) {
        bf16x8 bk = *(const bf16x8*)&lds_k[(j * 16 + llo) * LP + kk * 32 + lhi * 8];
#pragma unroll
        for (int i = 0; i < 2; i++)
          sacc[i][j] = __builtin_amdgcn_mfma_f32_16x16x32_bf16(aq[i], bk, sacc[i][j], 0, 0, 0);
      }
    }

#pragma unroll
    for (int i = 0; i < 2; i++)
#pragma unroll
      for (int j = 0; j < 8; j++)
#pragma unroll
        for (int r = 0; r < 4; r++)
          sacc[i][j][r] *= sc;

    if (kt == qi) {  // causal mask on the diagonal tile: col > row -> -inf
#pragma unroll
      for (int i = 0; i < 2; i++)
#pragma unroll
        for (int j = 0; j < 8; j++) {
          int coll = j * 16 + llo;
#pragma unroll
          for (int r = 0; r < 4; r++) {
            int rowl = wave * 32 + i * 16 + lhi * 4 + r;
            if (coll > rowl) sacc[i][j][r] = -1e30f;
          }
        }
    }

    // online softmax update (row spread across the 16 llo-lanes of same lhi)
    float alpha[2][4];
#pragma unroll
    for (int i = 0; i < 2; i++) {
#pragma unroll
      for (int r = 0; r < 4; r++) {
        float mx = sacc[i][0][r];
#pragma unroll
        for (int j = 1; j < 8; j++) mx = fmaxf(mx, sacc[i][j][r]);
#pragma unroll
        for (int off = 1; off < 16; off <<= 1)
          mx = fmaxf(mx, __shfl_xor(mx, off, 64));
        float mnew = fmaxf(mrow[i][r], mx);
        float al = __expf(mrow[i][r] - mnew);
        mrow[i][r] = mnew;
        alpha[i][r] = al;
        float rs = 0.f;
#pragma unroll
        for (int j = 0; j < 8; j++) {
          float e = __expf(sacc[i][j][r] - mnew);
          sacc[i][j][r] = e;
          rs += e;
        }
#pragma unroll
        for (int off = 1; off < 16; off <<= 1)
          rs += __shfl_xor(rs, off, 64);
        lrow[i][r] = lrow[i][r] * al + rs;
      }
    }

    // P -> LDS (wave writes/reads only its own 32 rows; in-wave DS ordering)
#pragma unroll
    for (int i = 0; i < 2; i++)
#pragma unroll
      for (int j = 0; j < 8; j++)
#pragma unroll
        for (int r = 0; r < 4; r++)
          lds_p[(wave * 32 + i * 16 + lhi * 4 + r) * LP + j * 16 + llo] = f2bf(sacc[i][j][r]);

#pragma unroll
    for (int i = 0; i < 2; i++)
#pragma unroll
      for (int j = 0; j < 8; j++)
#pragma unroll
        for (int r = 0; r < 4; r++)
          oacc[i][j][r] *= alpha[i][r];

    // O += P V   (V^T staged as [d][t], contraction over t)
#pragma unroll
    for (int kk = 0; kk < 4; kk++) {
      bf16x8 ap[2];
#pragma unroll
      for (int i = 0; i < 2; i++)
        ap[i] = *(const bf16x8*)&lds_p[(wave * 32 + i * 16 + llo) * LP + kk * 32 + lhi * 8];
#pragma unroll
      for (int j = 0; j < 8; j++) {
        bf16x8 bv = *(const bf16x8*)&lds_v[(j * 16 + llo) * LP + kk * 32 + lhi * 8];
#pragma unroll
        for (int i = 0; i < 2; i++)
          oacc[i][j] = __builtin_amdgcn_mfma_f32_16x16x32_bf16(ap[i], bv, oacc[i][j], 0, 0, 0);
      }
    }
    __syncthreads();
  }

  // epilogue: O /= l, write ctx[s,b,h*128+d]
#pragma unroll
  for (int i = 0; i < 2; i++) {
    float inv[4];
#pragma unroll
    for (int r = 0; r < 4; r++) inv[r] = 1.f / lrow[i][r];
#pragma unroll
    for (int j = 0; j < 8; j++) {
      int d = j * 16 + llo;
#pragma unroll
      for (int r = 0; r < 4; r++) {
        int s = qi * 128 + wave * 32 + i * 16 + lhi * 4 + r;
        ctx[((size_t)(s * BATCH + b)) * HIDN + h * DHEAD + d] = f2bf(oacc[i][j][r] * inv[r]);
      }
    }
  }
}

// ---------------- bias tail: fp32 copy into output slot 1 --------------------
__global__ __launch_bounds__(256) void bias_copy_kernel(
    const float* __restrict__ bsrc, float* __restrict__ dst) {
  int i = blockIdx.x * 256 + threadIdx.x;
  if (i < HIDN) dst[i] = bsrc[i];
}

extern "C" void kernel_launch(void* const* d_in, const int* in_sizes, int n_in,
                              void* d_out, int out_size, void* d_ws, size_t ws_size,
                              hipStream_t stream) {
  // Input mapping by unique element counts (mask shares W_dense's 4194304
  // count but precedes it in dict order -> take LAST match for W_dense).
  int i_hid = 0, i_w1 = 2, i_b1 = 3, i_w2 = 4, i_b2 = 5;
  for (int i = 0; i < n_in; i++) {
    int s = in_sizes[i];
    if (s == MROWS * HIDN)      i_hid = i;
    else if (s == HIDN * NQKV)  i_w1 = i;
    else if (s == NQKV)         i_b1 = i;
    else if (s == HIDN)         i_b2 = i;
  }
  for (int i = n_in - 1; i >= 0; i--)
    if (in_sizes[i] == HIDN * HIDN) { i_w2 = i; break; }

  const float* hidden  = (const float*)d_in[i_hid];
  const float* W_qkv   = (const float*)d_in[i_w1];
  const float* b_qkv   = (const float*)d_in[i_b1];
  const float* W_dense = (const float*)d_in[i_w2];
  const float* b_dense = (const float*)d_in[i_b2];
  float* out = (float*)d_out;   // fp32: reference output dtype

  // Workspace (72 MB peak):
  //   [0, 24M)  : Wq_t   (transpose#1 .. gemm_qkv)
  //   [0, 16M)  : ctx    (attn .. gemm_dense)  -- overlays dead Wq_t
  //   [16M,24M) : Wd_t   (transpose#2 .. gemm_dense)
  //   [24M,40M) : Qb   [40M,56M): Kb   [56M,72M): Vt
  // d_out bytes [0,16M) host hidden_c (bf16), dead before gemm_dense writes.
  char* ws = (char*)d_ws;
  u16* Wq_t = (u16*)(ws);
  u16* ctx  = (u16*)(ws);
  u16* Wd_t = (u16*)(ws + 16777216);
  u16* Qb   = (u16*)(ws + 25165824);
  u16* Kb   = (u16*)(ws + 41943040);
  u16* Vt   = (u16*)(ws + 58720256);
  u16* hidden_c = (u16*)d_out;  // bytes [0,16M) of d_out

  convert_hidden_kernel<<<dim3(MROWS * HIDN / 8 / 256), 256, 0, stream>>>(hidden, hidden_c);
  transpose_kernel<<<dim3(NQKV / 64, HIDN / 64), 256, 0, stream>>>(W_qkv, Wq_t, HIDN, NQKV);
  gemm_qkv_kernel<<<dim3(NQKV / 128, MROWS / 128), 256, 0, stream>>>(hidden_c, Wq_t, b_qkv, Qb, Kb, Vt);
  attn_kernel<<<dim3(S_LEN / 128, BATCH * NHEAD), 256, 0, stream>>>(Qb, Kb, Vt, ctx);
  transpose_kernel<<<dim3(HIDN / 64, HIDN / 64), 256, 0, stream>>>(W_dense, Wd_t, HIDN, HIDN);
  gemm_dense_kernel<<<dim3(HIDN / 128, MROWS / 128), 256, 0, stream>>>(ctx, Wd_t, out);
  bias_copy_kernel<<<dim3(8), 256, 0, stream>>>(b_dense, out + (size_t)MROWS * HIDN);
}

// Round 7
// 535.040 us; speedup vs baseline: 9.9298x; 1.2679x over previous
//
#include <hip/hip_runtime.h>
#include <cstdint>
#include <cstddef>

#define S_LEN 2048
#define BATCH 2
#define HIDN  2048
#define NHEAD 16
#define DHEAD 128
#define NQKV  6144   // 3*NHEAD*DHEAD
#define MROWS 4096   // S_LEN*BATCH

typedef unsigned short u16;
typedef __attribute__((ext_vector_type(8))) __bf16 bf16x8;
typedef __attribute__((ext_vector_type(4))) float f32x4;

__device__ __forceinline__ float bf2f(u16 u) {
  union { uint32_t i; float f; } v; v.i = ((uint32_t)u) << 16; return v.f;
}
__device__ __forceinline__ u16 f2bf(float f) {
  union { float f; uint32_t i; } v; v.f = f;
  uint32_t r = v.i + 0x7fffu + ((v.i >> 16) & 1u);
  return (u16)(r >> 16);
}

__device__ __forceinline__ void async_cp16(const u16* g, u16* l) {
  __builtin_amdgcn_global_load_lds(
      (const __attribute__((address_space(1))) void*)g,
      (__attribute__((address_space(3))) void*)l, 16, 0, 0);
}

// ---------------- hidden canonicalize: fp32[N] -> bf16[N] --------------------
__global__ __launch_bounds__(256) void convert_hidden_kernel(
    const float* __restrict__ src, u16* __restrict__ out) {
  size_t c = (size_t)blockIdx.x * 256 + threadIdx.x;  // chunk of 8 elements
  const float4* in = (const float4*)(src + c * 8);
  float4 v0 = in[0], v1 = in[1];
  u16 t[8] = {f2bf(v0.x), f2bf(v0.y), f2bf(v0.z), f2bf(v0.w),
              f2bf(v1.x), f2bf(v1.y), f2bf(v1.z), f2bf(v1.w)};
  *(uint4*)&out[c * 8] = *(const uint4*)t;
}

// ---------------- transpose+cast: fp32 in[R][C] -> bf16 out[C][R] ------------
__global__ __launch_bounds__(256) void transpose_kernel(
    const float* __restrict__ in, u16* __restrict__ out, int R, int C) {
  __shared__ u16 tile[64][72];
  const int bx = blockIdx.x * 64;  // col base in `in`
  const int by = blockIdx.y * 64;  // row base in `in`
  const int lx = threadIdx.x & 15, ly = threadIdx.x >> 4;
#pragma unroll
  for (int i = 0; i < 4; i++) {
    int r = ly * 4 + i;
    float4 v = *(const float4*)&in[(size_t)(by + r) * C + bx + lx * 4];
    tile[r][lx * 4 + 0] = f2bf(v.x); tile[r][lx * 4 + 1] = f2bf(v.y);
    tile[r][lx * 4 + 2] = f2bf(v.z); tile[r][lx * 4 + 3] = f2bf(v.w);
  }
  __syncthreads();
#pragma unroll
  for (int i = 0; i < 4; i++) {
    int oc = ly * 4 + i;  // out row = bx + oc
    ushort4 o;
    o.x = tile[lx * 4 + 0][oc]; o.y = tile[lx * 4 + 1][oc];
    o.z = tile[lx * 4 + 2][oc]; o.w = tile[lx * 4 + 3][oc];
    *(ushort4*)&out[(size_t)(bx + oc) * R + by + lx * 4] = o;
  }
}

// ---------------- QKV GEMM: [4096,2048] x Wt[6144,2048] + bias ---------------
__global__ __launch_bounds__(256) void gemm_qkv_kernel(
    const u16* __restrict__ A, const u16* __restrict__ Bt,
    const float* __restrict__ bias,
    u16* __restrict__ Qb, u16* __restrict__ Kb, u16* __restrict__ Vt) {
  __shared__ __align__(16) u16 lds_a[128 * 32];
  __shared__ __align__(16) u16 lds_b[128 * 32];
  const int tid = threadIdx.x;
  const int wave = tid >> 6, lane = tid & 63;
  const int lhi = lane >> 4, llo = lane & 15;
  const int m0 = blockIdx.y * 128, n0 = blockIdx.x * 128;
  const int wm = (wave >> 1) * 64, wn = (wave & 1) * 64;
  const int K = HIDN;

  f32x4 acc[4][4] = {};

  const int srow = tid >> 2;
  const int skoff = (tid & 3) * 8;
  const u16* ap0 = A + (size_t)(m0 + srow) * K + skoff;
  const u16* ap1 = A + (size_t)(m0 + 64 + srow) * K + skoff;
  const u16* bp0 = Bt + (size_t)(n0 + srow) * K + skoff;
  const u16* bp1 = Bt + (size_t)(n0 + 64 + srow) * K + skoff;
  u16* la0 = lds_a + tid * 8;
  u16* la1 = lds_a + 2048 + tid * 8;
  u16* lb0 = lds_b + tid * 8;
  u16* lb1 = lds_b + 2048 + tid * 8;

  for (int k0 = 0; k0 < K; k0 += 32) {
    async_cp16(ap0 + k0, la0);
    async_cp16(ap1 + k0, la1);
    async_cp16(bp0 + k0, lb0);
    async_cp16(bp1 + k0, lb1);
    __syncthreads();
    bf16x8 af[4], bfr[4];
#pragma unroll
    for (int i = 0; i < 4; i++)
      af[i] = *(const bf16x8*)&lds_a[(wm + i * 16 + llo) * 32 + lhi * 8];
#pragma unroll
    for (int j = 0; j < 4; j++)
      bfr[j] = *(const bf16x8*)&lds_b[(wn + j * 16 + llo) * 32 + lhi * 8];
#pragma unroll
    for (int i = 0; i < 4; i++)
#pragma unroll
      for (int j = 0; j < 4; j++)
        acc[i][j] = __builtin_amdgcn_mfma_f32_16x16x32_bf16(af[i], bfr[j], acc[i][j], 0, 0, 0);
    __syncthreads();
  }

#pragma unroll
  for (int i = 0; i < 4; i++) {
#pragma unroll
    for (int j = 0; j < 4; j++) {
      int col = n0 + wn + j * 16 + llo;       // 0..6143
      int h = col / 384;
      int rr = col - h * 384;
      int part = rr >> 7;                     // 0=q 1=k 2=v
      int d = rr & 127;
      float bv = bias[col];
#pragma unroll
      for (int r = 0; r < 4; r++) {
        int row = m0 + wm + i * 16 + lhi * 4 + r;  // 0..4095
        int s = row >> 1, b = row & 1;
        int bh = b * NHEAD + h;
        u16 o = f2bf(acc[i][j][r] + bv);
        if (part == 0)      Qb[((size_t)bh * S_LEN + s) * DHEAD + d] = o;
        else if (part == 1) Kb[((size_t)bh * S_LEN + s) * DHEAD + d] = o;
        else                Vt[((size_t)bh * DHEAD + d) * S_LEN + s] = o;
      }
    }
  }
}

// ------------- dense GEMM: ctx[4096,2048] x Wt[2048,2048] -> fp32 out --------
__global__ __launch_bounds__(256) void gemm_dense_kernel(
    const u16* __restrict__ A, const u16* __restrict__ Bt,
    float* __restrict__ out) {
  __shared__ __align__(16) u16 lds_a[128 * 32];
  __shared__ __align__(16) u16 lds_b[128 * 32];
  const int tid = threadIdx.x;
  const int wave = tid >> 6, lane = tid & 63;
  const int lhi = lane >> 4, llo = lane & 15;
  const int m0 = blockIdx.y * 128, n0 = blockIdx.x * 128;
  const int wm = (wave >> 1) * 64, wn = (wave & 1) * 64;
  const int K = HIDN;

  f32x4 acc[4][4] = {};

  const int srow = tid >> 2;
  const int skoff = (tid & 3) * 8;
  const u16* ap0 = A + (size_t)(m0 + srow) * K + skoff;
  const u16* ap1 = A + (size_t)(m0 + 64 + srow) * K + skoff;
  const u16* bp0 = Bt + (size_t)(n0 + srow) * K + skoff;
  const u16* bp1 = Bt + (size_t)(n0 + 64 + srow) * K + skoff;
  u16* la0 = lds_a + tid * 8;
  u16* la1 = lds_a + 2048 + tid * 8;
  u16* lb0 = lds_b + tid * 8;
  u16* lb1 = lds_b + 2048 + tid * 8;

  for (int k0 = 0; k0 < K; k0 += 32) {
    async_cp16(ap0 + k0, la0);
    async_cp16(ap1 + k0, la1);
    async_cp16(bp0 + k0, lb0);
    async_cp16(bp1 + k0, lb1);
    __syncthreads();
    bf16x8 af[4], bfr[4];
#pragma unroll
    for (int i = 0; i < 4; i++)
      af[i] = *(const bf16x8*)&lds_a[(wm + i * 16 + llo) * 32 + lhi * 8];
#pragma unroll
    for (int j = 0; j < 4; j++)
      bfr[j] = *(const bf16x8*)&lds_b[(wn + j * 16 + llo) * 32 + lhi * 8];
#pragma unroll
    for (int i = 0; i < 4; i++)
#pragma unroll
      for (int j = 0; j < 4; j++)
        acc[i][j] = __builtin_amdgcn_mfma_f32_16x16x32_bf16(af[i], bfr[j], acc[i][j], 0, 0, 0);
    __syncthreads();
  }

  // fp32 epilogue: reference output dtype is float32
#pragma unroll
  for (int i = 0; i < 4; i++)
#pragma unroll
    for (int j = 0; j < 4; j++) {
      int col = n0 + wn + j * 16 + llo;
#pragma unroll
      for (int r = 0; r < 4; r++) {
        int row = m0 + wm + i * 16 + lhi * 4 + r;
        out[(size_t)row * HIDN + col] = acc[i][j][r];
      }
    }
}

// ---------------- flash attention (causal), one block per (q-tile, bh) -------
// Q in registers; lds_p aliases lds_k; LP=132 (2-bank row skew, <=2-way).
__global__ __launch_bounds__(256, 2) void attn_kernel(
    const u16* __restrict__ Qb, const u16* __restrict__ Kb,
    const u16* __restrict__ Vt, u16* __restrict__ ctx) {
  const int bh = blockIdx.y;   // 0..31
  const int b = bh >> 4, h = bh & 15;
  // balance swizzle: co-resident pairs (blockIdx.x, bh) and (blockIdx.x, bh+16)
  // get qi and 15-qi -> uniform ~17 tile-steps per CU.
  const int qi = (b == 0) ? blockIdx.x : (15 - blockIdx.x);
  const int tid = threadIdx.x;
  const int wave = tid >> 6, lane = tid & 63;
  const int lhi = lane >> 4, llo = lane & 15;
  const int LP = 132;
  __shared__ __align__(16) u16 lds_kp[128 * 132];  // K tile, then P (aliased)
  __shared__ __align__(16) u16 lds_v[128 * 132];   // V^T tile [d][t]

  // ---- Q A-fragments in registers (once per block) ----
  bf16x8 aq[2][4];
  {
    const u16* qsrc = Qb + ((size_t)bh * S_LEN + qi * 128) * DHEAD;
#pragma unroll
    for (int i = 0; i < 2; i++)
#pragma unroll
      for (int kk = 0; kk < 4; kk++)
        aq[i][kk] = *(const bf16x8*)&qsrc[(size_t)(wave * 32 + i * 16 + llo) * DHEAD + kk * 32 + lhi * 8];
  }

  f32x4 oacc[2][8] = {};
  float mrow[2][4], lrow[2][4];
#pragma unroll
  for (int i = 0; i < 2; i++)
#pragma unroll
    for (int r = 0; r < 4; r++) { mrow[i][r] = -1e30f; lrow[i][r] = 0.f; }

  const float sc = 0.08838834764831845f;  // 1/sqrt(128)

  for (int kt = 0; kt <= qi; kt++) {
    const u16* ksrc = Kb + ((size_t)bh * S_LEN + kt * 128) * DHEAD;
    const u16* vsrc = Vt + (size_t)bh * DHEAD * S_LEN + kt * 128;
#pragma unroll
    for (int p = 0; p < 8; p++) {
      int idx = p * 256 + tid;
      int r = idx >> 4, sg = (idx & 15) * 8;
      *(uint4*)&lds_kp[r * LP + sg] = *(const uint4*)&ksrc[r * DHEAD + sg];
      *(uint4*)&lds_v[r * LP + sg] = *(const uint4*)&vsrc[(size_t)r * S_LEN + sg];
    }
    __syncthreads();

    // S = Q K^T  (wave owns 32 q-rows x 128 t-cols)
    f32x4 sacc[2][8] = {};
#pragma unroll
    for (int kk = 0; kk < 4; kk++) {
#pragma unroll
      for (int j = 0; j < 8; j++) {
        bf16x8 bk = *(const bf16x8*)&lds_kp[(j * 16 + llo) * LP + kk * 32 + lhi * 8];
#pragma unroll
        for (int i = 0; i < 2; i++)
          sacc[i][j] = __builtin_amdgcn_mfma_f32_16x16x32_bf16(aq[i][kk], bk, sacc[i][j], 0, 0, 0);
      }
    }
    __syncthreads();  // all waves done reading K before P overwrites lds_kp

#pragma unroll
    for (int i = 0; i < 2; i++)
#pragma unroll
      for (int j = 0; j < 8; j++)
#pragma unroll
        for (int r = 0; r < 4; r++)
          sacc[i][j][r] *= sc;

    if (kt == qi) {  // causal mask on the diagonal tile: col > row -> -inf
#pragma unroll
      for (int i = 0; i < 2; i++)
#pragma unroll
        for (int j = 0; j < 8; j++) {
          int coll = j * 16 + llo;
#pragma unroll
          for (int r = 0; r < 4; r++) {
            int rowl = wave * 32 + i * 16 + lhi * 4 + r;
            if (coll > rowl) sacc[i][j][r] = -1e30f;
          }
        }
    }

    // online softmax update (row spread across the 16 llo-lanes)
    float alpha[2][4];
#pragma unroll
    for (int i = 0; i < 2; i++) {
#pragma unroll
      for (int r = 0; r < 4; r++) {
        float mx = sacc[i][0][r];
#pragma unroll
        for (int j = 1; j < 8; j++) mx = fmaxf(mx, sacc[i][j][r]);
#pragma unroll
        for (int off = 1; off < 16; off <<= 1)
          mx = fmaxf(mx, __shfl_xor(mx, off, 64));
        float mnew = fmaxf(mrow[i][r], mx);
        float al = __expf(mrow[i][r] - mnew);
        mrow[i][r] = mnew;
        alpha[i][r] = al;
        float rs = 0.f;
#pragma unroll
        for (int j = 0; j < 8; j++) {
          float e = __expf(sacc[i][j][r] - mnew);
          sacc[i][j][r] = e;
          rs += e;
        }
#pragma unroll
        for (int off = 1; off < 16; off <<= 1)
          rs += __shfl_xor(rs, off, 64);
        lrow[i][r] = lrow[i][r] * al + rs;
      }
    }

    // P -> LDS (aliased over K; wave writes/reads only its own 32 rows)
#pragma unroll
    for (int i = 0; i < 2; i++)
#pragma unroll
      for (int j = 0; j < 8; j++)
#pragma unroll
        for (int r = 0; r < 4; r++)
          lds_kp[(wave * 32 + i * 16 + lhi * 4 + r) * LP + j * 16 + llo] = f2bf(sacc[i][j][r]);

#pragma unroll
    for (int i = 0; i < 2; i++)
#pragma unroll
      for (int j = 0; j < 8; j++)
#pragma unroll
        for (int r = 0; r < 4; r++)
          oacc[i][j][r] *= alpha[i][r];

    // O += P V   (V^T staged as [d][t], contraction over t)
#pragma unroll
    for (int kk = 0; kk < 4; kk++) {
      bf16x8 ap[2];
#pragma unroll
      for (int i = 0; i < 2; i++)
        ap[i] = *(const bf16x8*)&lds_kp[(wave * 32 + i * 16 + llo) * LP + kk * 32 + lhi * 8];
#pragma unroll
      for (int j = 0; j < 8; j++) {
        bf16x8 bv = *(const bf16x8*)&lds_v[(j * 16 + llo) * LP + kk * 32 + lhi * 8];
#pragma unroll
        for (int i = 0; i < 2; i++)
          oacc[i][j] = __builtin_amdgcn_mfma_f32_16x16x32_bf16(ap[i], bv, oacc[i][j], 0, 0, 0);
      }
    }
    __syncthreads();  // P/V reads done before next staging
  }

  // epilogue: O /= l, write ctx[s,b,h*128+d]
#pragma unroll
  for (int i = 0; i < 2; i++) {
    float inv[4];
#pragma unroll
    for (int r = 0; r < 4; r++) inv[r] = 1.f / lrow[i][r];
#pragma unroll
    for (int j = 0; j < 8; j++) {
      int d = j * 16 + llo;
#pragma unroll
      for (int r = 0; r < 4; r++) {
        int s = qi * 128 + wave * 32 + i * 16 + lhi * 4 + r;
        ctx[((size_t)(s * BATCH + b)) * HIDN + h * DHEAD + d] = f2bf(oacc[i][j][r] * inv[r]);
      }
    }
  }
}

// ---------------- bias tail: fp32 copy into output slot 1 --------------------
__global__ __launch_bounds__(256) void bias_copy_kernel(
    const float* __restrict__ bsrc, float* __restrict__ dst) {
  int i = blockIdx.x * 256 + threadIdx.x;
  if (i < HIDN) dst[i] = bsrc[i];
}

extern "C" void kernel_launch(void* const* d_in, const int* in_sizes, int n_in,
                              void* d_out, int out_size, void* d_ws, size_t ws_size,
                              hipStream_t stream) {
  // Input mapping by unique element counts (mask shares W_dense's 4194304
  // count but precedes it in dict order -> take LAST match for W_dense).
  int i_hid = 0, i_w1 = 2, i_b1 = 3, i_w2 = 4, i_b2 = 5;
  for (int i = 0; i < n_in; i++) {
    int s = in_sizes[i];
    if (s == MROWS * HIDN)      i_hid = i;
    else if (s == HIDN * NQKV)  i_w1 = i;
    else if (s == NQKV)         i_b1 = i;
    else if (s == HIDN)         i_b2 = i;
  }
  for (int i = n_in - 1; i >= 0; i--)
    if (in_sizes[i] == HIDN * HIDN) { i_w2 = i; break; }

  const float* hidden  = (const float*)d_in[i_hid];
  const float* W_qkv   = (const float*)d_in[i_w1];
  const float* b_qkv   = (const float*)d_in[i_b1];
  const float* W_dense = (const float*)d_in[i_w2];
  const float* b_dense = (const float*)d_in[i_b2];
  float* out = (float*)d_out;   // fp32: reference output dtype

  // Workspace (72 MB peak):
  //   [0, 24M)  : Wq_t   (transpose#1 .. gemm_qkv)
  //   [0, 16M)  : ctx    (attn .. gemm_dense)  -- overlays dead Wq_t
  //   [16M,24M) : Wd_t   (transpose#2 .. gemm_dense)
  //   [24M,40M) : Qb   [40M,56M): Kb   [56M,72M): Vt
  // d_out bytes [0,16M) host hidden_c (bf16), dead before gemm_dense writes.
  char* ws = (char*)d_ws;
  u16* Wq_t = (u16*)(ws);
  u16* ctx  = (u16*)(ws);
  u16* Wd_t = (u16*)(ws + 16777216);
  u16* Qb   = (u16*)(ws + 25165824);
  u16* Kb   = (u16*)(ws + 41943040);
  u16* Vt   = (u16*)(ws + 58720256);
  u16* hidden_c = (u16*)d_out;  // bytes [0,16M) of d_out

  convert_hidden_kernel<<<dim3(MROWS * HIDN / 8 / 256), 256, 0, stream>>>(hidden, hidden_c);
  transpose_kernel<<<dim3(NQKV / 64, HIDN / 64), 256, 0, stream>>>(W_qkv, Wq_t, HIDN, NQKV);
  gemm_qkv_kernel<<<dim3(NQKV / 128, MROWS / 128), 256, 0, stream>>>(hidden_c, Wq_t, b_qkv, Qb, Kb, Vt);
  attn_kernel<<<dim3(S_LEN / 128, BATCH * NHEAD), 256, 0, stream>>>(Qb, Kb, Vt, ctx);
  transpose_kernel<<<dim3(HIDN / 64, HIDN / 64), 256, 0, stream>>>(W_dense, Wd_t, HIDN, HIDN);
  gemm_dense_kernel<<<dim3(HIDN / 128, MROWS / 128), 256, 0, stream>>>(ctx, Wd_t, out);
  bias_copy_kernel<<<dim3(8), 256, 0, stream>>>(b_dense, out + (size_t)MROWS * HIDN);
}